// Round 12
// baseline (937.527 us; speedup 1.0000x reference)
//
#include <hip/hip_runtime.h>
#include <hip/hip_bf16.h>
#include <stdint.h>

// GroupCommunication fused: 65536 tok x 1024 ch; 16 blocks x 64; 2 heads x 32.
// R12: persistent R4. 512 thr (8 waves, 2 g per wave), STATIC 64KB LDS ->
// compiler sees the 2-WG/CU bound and allows VGPR up to 128 (R11's spill was
// the dynamic-LDS heuristic pinning 64). Grid 512, each WG loops 8 tiles of
// 16 tokens; next tile's x prefetched into 8 named float4 right after B2
// (covered by PH3(0)+PH1(1)+PH2(1) spans). Schedule per tile (R4-verified):
// PH1(0) |B| PH2(0) |B| XLOAD'+accinit+PH3(0)+PH1(1) |B| PH2(1) |B|
// PH3(1)+store+XPACK'.

typedef __attribute__((ext_vector_type(8))) short bf16x8;
typedef __attribute__((ext_vector_type(4))) float f32x4;

#define NTOK   65536
#define DM     1024
#define TT     16
#define NT     8                       // tiles per WG; grid = NTOK/(TT*NT) = 512
#define QSCALE 0.17677669529663687f    // 32^-0.5
#define LOG2E  1.4426950408889634f

static __device__ __forceinline__ unsigned short f2bf(float f) {
  union { __hip_bfloat16 h; unsigned short s; } cv;
  cv.h = __float2bfloat16(f);          // RNE
  return cv.s;
}

static __device__ __forceinline__ unsigned int pk2(float a, float b) {
  return (unsigned int)f2bf(a) | ((unsigned int)f2bf(b) << 16);
}

static __device__ __forceinline__ bf16x8 pack8(float4 a, float4 b) {
  bf16x8 r;
  r[0] = (short)f2bf(a.x); r[1] = (short)f2bf(a.y);
  r[2] = (short)f2bf(a.z); r[3] = (short)f2bf(a.w);
  r[4] = (short)f2bf(b.x); r[5] = (short)f2bf(b.y);
  r[6] = (short)f2bf(b.z); r[7] = (short)f2bf(b.w);
  return r;
}

union FragCast { uint4 u4; bf16x8 v; uint2 u2[2]; unsigned int u[4]; };

// ---------------------------------------------------------------------------
// Prologue: pack wq(scaled),wk,wv,wf fp32 [g][i][o] -> bf16 fragment stream.
// frag elem j = W[k = kk*32 + 8*(lane>>4) + j][o = nf*16 + (lane&15)].
// A- and B-side consumers always use the identical (lane,j)->k map, so any
// HW k-permutation cancels.
// ---------------------------------------------------------------------------
__global__ void build_wfrag(const float* __restrict__ wq, const float* __restrict__ wk,
                            const float* __restrict__ wv, const float* __restrict__ wf,
                            uint4* __restrict__ wfrag) {
  int tid = blockIdx.x * 256 + threadIdx.x;
  if (tid >= 4 * 16 * 2 * 4 * 64) return;
  int lane =  tid        & 63;
  int nf   = (tid >> 6)  & 3;
  int kk   = (tid >> 8)  & 1;
  int g    = (tid >> 9)  & 15;
  int mat  =  tid >> 13;
  const float* w = (mat == 0) ? wq : (mat == 1) ? wk : (mat == 2) ? wv : wf;
  float sc = (mat == 0) ? QSCALE : 1.0f;
  int o  = nf * 16 + (lane & 15);
  int kb = kk * 32 + 8 * (lane >> 4);
  unsigned int packed[4];
#pragma unroll
  for (int jj = 0; jj < 4; ++jj) {
    unsigned short lo = f2bf(w[(g * 64 + kb + 2 * jj    ) * 64 + o] * sc);
    unsigned short hi = f2bf(w[(g * 64 + kb + 2 * jj + 1) * 64 + o] * sc);
    packed[jj] = (unsigned int)lo | ((unsigned int)hi << 16);
  }
  uint4 u; u.x = packed[0]; u.y = packed[1]; u.z = packed[2]; u.w = packed[3];
  wfrag[tid] = u;
}

// ---------------------------------------------------------------------------
// Phase macros (textual expansion; h_ must be a literal 0/1). Identical to
// the verified R4 kernel.
// ---------------------------------------------------------------------------
#define PH1(h_) do {                                                          \
  _Pragma("unroll")                                                           \
  for (int gi = 0; gi < 2; ++gi) {                                            \
    const int g = 2 * w + gi;                                                 \
    _Pragma("unroll")                                                         \
    for (int mat = 0; mat < 2; ++mat) {      /* q, k (swapped orientation) */ \
      const float* bp = mat ? bk : bq;                                        \
      const float bsc = mat ? 1.0f : QSCALE;                                  \
      unsigned short* dst = mat ? s_k : s_q;                                  \
      _Pragma("unroll")                                                       \
      for (int nf2 = 0; nf2 < 2; ++nf2) {                                     \
        const int nf = 2 * (h_) + nf2;                                        \
        float4 b4 = *(const float4*)&bp[g * 64 + nf * 16 + 4 * lq];           \
        f32x4 a1 = {b4.x * bsc, b4.y * bsc, b4.z * bsc, b4.w * bsc};          \
        _Pragma("unroll")                                                     \
        for (int kk = 0; kk < 2; ++kk) {                                      \
          FragCast fc;                                                        \
          fc.u4 = wfrag[(((mat * 16 + g) * 2 + kk) * 4 + nf) * 64 + lane];    \
          a1 = __builtin_amdgcn_mfma_f32_16x16x32_bf16(fc.v, afr[gi][kk], a1, 0, 0, 0); \
        }                                                                     \
        /* D[o][t]: col t=lr, rows o=nf*16+4lq+r -> d_h = nf2*16+4lq+r */     \
        uint2 w2; w2.x = pk2(a1[0], a1[1]); w2.y = pk2(a1[2], a1[3]);         \
        const int blk = (16 * (2 * nf2 + (lq >> 1)) + g) ^ (lr & 7);          \
        *(uint2*)&dst[lr * 512 + blk * 8 + 4 * (lq & 1)] = w2;                \
      }                                                                       \
    }                                                                         \
    _Pragma("unroll")                                                         \
    for (int nf2 = 0; nf2 < 2; ++nf2) {      /* v (original orientation) */   \
      const int nf = 2 * (h_) + nf2;                                          \
      const float bias = bv[g * 64 + nf * 16 + lr];                           \
      f32x4 a1 = {bias, bias, bias, bias};                                    \
      _Pragma("unroll")                                                       \
      for (int kk = 0; kk < 2; ++kk) {                                        \
        FragCast fc;                                                          \
        fc.u4 = wfrag[(((2 * 16 + g) * 2 + kk) * 4 + nf) * 64 + lane];        \
        a1 = __builtin_amdgcn_mfma_f32_16x16x32_bf16(afr[gi][kk], fc.v, a1, 0, 0, 0); \
      }                                                                       \
      /* D[t][o]: col o (d_h = nf2*16+lr), rows t=4lq+r; f = g */             \
      const int L = 16 * (g >> 2) + lr;                                       \
      const int jj = g & 3;                                                   \
      _Pragma("unroll")                                                       \
      for (int r = 0; r < 4; ++r)                                             \
        s_v[((4 * lq + r) * 2 + nf2) * 256 + L * 4 + jj] = f2bf(a1[r]);       \
    }                                                                         \
  }                                                                           \
} while (0)

#define PH2() do {                                                            \
  _Pragma("unroll")                                                           \
  for (int tt = 0; tt < 2; ++tt) {                                            \
    const int t = 2 * w + tt;                                                 \
    f32x4 zero = {0.f, 0.f, 0.f, 0.f};                                        \
    FragCast qa, ka;                                                          \
    const int blk = lane ^ (t & 7);                                           \
    qa.u4 = *(const uint4*)&s_q[t * 512 + blk * 8];                           \
    ka.u4 = *(const uint4*)&s_k[t * 512 + blk * 8];                           \
    /* D[f][g]: col g=lr, rows f=4lq+r (K=32 = full head dim) */              \
    f32x4 sc4 = __builtin_amdgcn_mfma_f32_16x16x32_bf16(ka.v, qa.v, zero, 0, 0, 0); \
    float m = fmaxf(fmaxf(sc4[0], sc4[1]), fmaxf(sc4[2], sc4[3]));            \
    m = fmaxf(m, __shfl_xor(m, 16));                                          \
    m = fmaxf(m, __shfl_xor(m, 32));                                          \
    float p0 = exp2f((sc4[0] - m) * LOG2E);                                   \
    float p1 = exp2f((sc4[1] - m) * LOG2E);                                   \
    float p2 = exp2f((sc4[2] - m) * LOG2E);                                   \
    float p3 = exp2f((sc4[3] - m) * LOG2E);                                   \
    float s = p0 + p1 + p2 + p3;                                              \
    s += __shfl_xor(s, 16);                                                   \
    s += __shfl_xor(s, 32);                                                   \
    const float inv = __fdividef(1.0f, s);                                    \
    FragCast pa;               /* P[g=lr][f=4lq+jj] at slots jj 0..3 */       \
    pa.u[0] = pk2(p0 * inv, p1 * inv);                                        \
    pa.u[1] = pk2(p2 * inv, p3 * inv);                                        \
    pa.u[2] = 0; pa.u[3] = 0;                                                 \
    _Pragma("unroll")                                                         \
    for (int nf = 0; nf < 2; ++nf) {                                          \
      FragCast va;             /* V[f=4lq+jj][d=nf*16+lr] at slots jj 0..3 */ \
      va.u2[0] = *(const uint2*)&s_v[(t * 2 + nf) * 256 + lane * 4];          \
      va.u[2] = 0; va.u[3] = 0;                                               \
      f32x4 o4 = __builtin_amdgcn_mfma_f32_16x16x32_bf16(va.v, pa.v, zero, 0, 0, 0); \
      /* D[d][g]: col g=lr, rows d=nf*16+4lq+r */                             \
      uint2 w2; w2.x = pk2(o4[0], o4[1]); w2.y = pk2(o4[2], o4[3]);           \
      const int ablk = (16 * (2 * nf + (lq >> 1)) + lr) ^ (t & 7);            \
      *(uint2*)&s_att[t * 512 + ablk * 8 + 4 * (lq & 1)] = w2;                \
    }                                                                         \
  }                                                                           \
} while (0)

#define PH3(h_) do {                                                          \
  _Pragma("unroll")                                                           \
  for (int gi = 0; gi < 2; ++gi) {                                            \
    const int g = 2 * w + gi;                                                 \
    FragCast aa;               /* att[t=lr][g][d=8lq+j] -> B[k][t] */         \
    const int blk = (16 * lq + g) ^ (lr & 7);                                 \
    aa.u4 = *(const uint4*)&s_att[lr * 512 + blk * 8];                        \
    _Pragma("unroll")                                                         \
    for (int nf = 0; nf < 4; ++nf) {                                          \
      FragCast fc;                                                            \
      fc.u4 = wfrag[(((3 * 16 + g) * 2 + (h_)) * 4 + nf) * 64 + lane];        \
      acc[gi][nf] = __builtin_amdgcn_mfma_f32_16x16x32_bf16(fc.v, aa.v, acc[gi][nf], 0, 0, 0); \
    }                                                                         \
  }                                                                           \
} while (0)

// x loads/pack for a tile: per wave 2 g's x 2 kk x 2 float4 = 8 named regs.
#define XLOAD(tokbase_) do {                                                  \
  const float* xr = x + ((tokbase_) + lr) * DM + 2 * w * 64;                  \
  xA0 = *(const float4*)(xr + 8 * lq);                                        \
  xA1 = *(const float4*)(xr + 8 * lq + 4);                                    \
  xA2 = *(const float4*)(xr + 32 + 8 * lq);                                   \
  xA3 = *(const float4*)(xr + 32 + 8 * lq + 4);                               \
  xB0 = *(const float4*)(xr + 64 + 8 * lq);                                   \
  xB1 = *(const float4*)(xr + 64 + 8 * lq + 4);                               \
  xB2 = *(const float4*)(xr + 96 + 8 * lq);                                   \
  xB3 = *(const float4*)(xr + 96 + 8 * lq + 4);                               \
} while (0)

#define XPACK() do {                                                          \
  afr[0][0] = pack8(xA0, xA1);                                                \
  afr[0][1] = pack8(xA2, xA3);                                                \
  afr[1][0] = pack8(xB0, xB1);                                                \
  afr[1][1] = pack8(xB2, xB3);                                                \
} while (0)

// ---------------------------------------------------------------------------
__global__ __launch_bounds__(512, 4)
void fused_pers16(const float* __restrict__ x,
                  const float* __restrict__ bq, const float* __restrict__ bk,
                  const float* __restrict__ bv, const float* __restrict__ bfb,
                  const uint4* __restrict__ wfrag,
                  float* __restrict__ out) {
  // STATIC 64KB LDS (visible occupancy bound -> sane regalloc).
  // Per-head fragment streams: [t(16)][blk(64)] x 16B. frag(t,L) holds
  // M[t][c = L&15][d = 8*(L>>4)+j]; stored at blk = L ^ (t&7).   16KB each.
  __shared__ __align__(16) unsigned short s_q  [16 * 512];
  __shared__ __align__(16) unsigned short s_k  [16 * 512];
  __shared__ __align__(16) unsigned short s_att[16 * 512];
  // v stream: [t][nf(2)][L(64)] x 4 shorts; frag = V[f=4*(L>>4)+jj][d=nf*16+(L&15)]
  __shared__ __align__(16) unsigned short s_v  [16 * 2 * 256];

  const int tid  = threadIdx.x;
  const int w    = tid >> 6;      // 8 waves; g = 2w+gi, t = 2w+tt
  const int lane = tid & 63;
  const int lr   = lane & 15;
  const int lq   = lane >> 4;

  bf16x8 afr[2][2];               // current tile's x fragments
  float4 xA0, xA1, xA2, xA3, xB0, xB1, xB2, xB3;   // prefetch staging
  f32x4 acc[2][4];                // [gi][nf] final-linear accumulators

  const long base = (long)blockIdx.x * (NT * TT);
  XLOAD(base);
  XPACK();

  for (int it = 0; it < NT; ++it) {
    const long tok0 = base + (long)it * TT;

    PH1(0);
    __syncthreads();                       // B1
    PH2();
    __syncthreads();                       // B2

    if (it + 1 < NT) XLOAD(tok0 + TT);     // in flight across 3 phases

    // acc init with final bias; consume att(h0); build h1 q/k/v
#pragma unroll
    for (int gi = 0; gi < 2; ++gi) {
      const int g = 2 * w + gi;
#pragma unroll
      for (int nf = 0; nf < 4; ++nf) {
        float4 b4 = *(const float4*)&bfb[g * 64 + nf * 16 + 4 * lq];
        acc[gi][nf][0] = b4.x; acc[gi][nf][1] = b4.y;
        acc[gi][nf][2] = b4.z; acc[gi][nf][3] = b4.w;
      }
    }
    PH3(0);
    PH1(1);
    __syncthreads();                       // B3
    PH2();
    __syncthreads();                       // B4
    PH3(1);

    // store out: D[o][t] -> one float4 per nf
#pragma unroll
    for (int gi = 0; gi < 2; ++gi) {
      const int g = 2 * w + gi;
#pragma unroll
      for (int nf = 0; nf < 4; ++nf) {
        float4 o4;
        o4.x = acc[gi][nf][0]; o4.y = acc[gi][nf][1];
        o4.z = acc[gi][nf][2]; o4.w = acc[gi][nf][3];
        *(float4*)&out[(tok0 + lr) * DM + g * 64 + nf * 16 + 4 * lq] = o4;
      }
    }

    if (it + 1 < NT) XPACK();
    // No extra barrier needed: next PH1(0) writes s_q/k/v (last read before
    // B4); next PH2(0)'s s_att writes are separated from PH3(1) reads by B1.
  }
}

// ---------------------------------------------------------------------------
extern "C" void kernel_launch(void* const* d_in, const int* in_sizes, int n_in,
                              void* d_out, int out_size, void* d_ws, size_t ws_size,
                              hipStream_t stream) {
  const float* x   = (const float*)d_in[0];
  const float* wq  = (const float*)d_in[1];
  const float* bq_ = (const float*)d_in[2];
  const float* wk  = (const float*)d_in[3];
  const float* bk_ = (const float*)d_in[4];
  const float* wv  = (const float*)d_in[5];
  const float* bv_ = (const float*)d_in[6];
  const float* wf  = (const float*)d_in[7];
  const float* bf_ = (const float*)d_in[8];
  (void)in_sizes; (void)n_in; (void)out_size; (void)ws_size;

  uint4* wfrag = (uint4*)d_ws;   // 4*16*2*4*64 frags * 16B = 512 KiB

  build_wfrag<<<128, 256, 0, stream>>>(wq, wk, wv, wf, wfrag);
  fused_pers16<<<NTOK / (NT * TT), 512, 0, stream>>>(x, bq_, bk_, bv_, bf_,
                                                     wfrag, (float*)d_out);
}

// Round 13
// 346.149 us; speedup vs baseline: 2.7084x; 2.7084x over previous
//
#include <hip/hip_runtime.h>
#include <hip/hip_bf16.h>
#include <stdint.h>

// GroupCommunication fused: 65536 tok x 1024 ch; 16 blocks x 64; 2 heads x 32.
// R13: persistent R9. Grid 256 (1 WG/CU, 160KB dynamic LDS), 1024 thr
// (16 waves, one g per wave), loop over NT=8 tiles of 32 tokens.
// Same 4 barriers per tile as R9; the loop-back span [B4 .. B1] contains
// PH3+stores of tile i AND x-prefetch+PH1(0) of tile i+1 (no extra barrier
// needed: q/k/v last read before B4; a0/a1 next written after next B1).
// x-prefetch is done in two 4-float4 half-batches INSIDE the tail span so
// the cross-barrier live set stays at R9's ~52 VGPR (the 64-VGPR wall:
// R5/R7/R10/R11/R12 all spilled when exceeding it).
// Per tile: PH1(0) |B1| PH2->a0 |B2| PH1(1) |B3| LOADF+PH2->a1 |B4|
//           [xload-m0, PH3+store, pack-m0, xload-m1, pack-m1]  -> loop.

typedef __attribute__((ext_vector_type(8))) short bf16x8;
typedef __attribute__((ext_vector_type(4))) float f32x4;

#define NTOK   65536
#define DM     1024
#define TILE   32
#define NT     8                       // tiles per WG; grid = NTOK/(TILE*NT) = 256
#define QSCALE 0.17677669529663687f    // 32^-0.5
#define LOG2E  1.4426950408889634f

static __device__ __forceinline__ unsigned short f2bf(float f) {
  union { __hip_bfloat16 h; unsigned short s; } cv;
  cv.h = __float2bfloat16(f);          // RNE
  return cv.s;
}

static __device__ __forceinline__ unsigned int pk2(float a, float b) {
  return (unsigned int)f2bf(a) | ((unsigned int)f2bf(b) << 16);
}

static __device__ __forceinline__ bf16x8 pack8(float4 a, float4 b) {
  bf16x8 r;
  r[0] = (short)f2bf(a.x); r[1] = (short)f2bf(a.y);
  r[2] = (short)f2bf(a.z); r[3] = (short)f2bf(a.w);
  r[4] = (short)f2bf(b.x); r[5] = (short)f2bf(b.y);
  r[6] = (short)f2bf(b.z); r[7] = (short)f2bf(b.w);
  return r;
}

union FragCast { uint4 u4; bf16x8 v; uint2 u2[2]; unsigned int u[4]; };

// ---------------------------------------------------------------------------
// Prologue: pack wq(scaled),wk,wv,wf fp32 [g][i][o] -> bf16 fragment stream.
// frag elem j = W[k = kk*32 + 8*(lane>>4) + j][o = nf*16 + (lane&15)].
// A- and B-side consumers always use the identical (lane,j)->k map.
// ---------------------------------------------------------------------------
__global__ void build_wfrag(const float* __restrict__ wq, const float* __restrict__ wk,
                            const float* __restrict__ wv, const float* __restrict__ wf,
                            uint4* __restrict__ wfrag) {
  int tid = blockIdx.x * 256 + threadIdx.x;
  if (tid >= 4 * 16 * 2 * 4 * 64) return;
  int lane =  tid        & 63;
  int nf   = (tid >> 6)  & 3;
  int kk   = (tid >> 8)  & 1;
  int g    = (tid >> 9)  & 15;
  int mat  =  tid >> 13;
  const float* w = (mat == 0) ? wq : (mat == 1) ? wk : (mat == 2) ? wv : wf;
  float sc = (mat == 0) ? QSCALE : 1.0f;
  int o  = nf * 16 + (lane & 15);
  int kb = kk * 32 + 8 * (lane >> 4);
  unsigned int packed[4];
#pragma unroll
  for (int jj = 0; jj < 4; ++jj) {
    unsigned short lo = f2bf(w[(g * 64 + kb + 2 * jj    ) * 64 + o] * sc);
    unsigned short hi = f2bf(w[(g * 64 + kb + 2 * jj + 1) * 64 + o] * sc);
    packed[jj] = (unsigned int)lo | ((unsigned int)hi << 16);
  }
  uint4 u; u.x = packed[0]; u.y = packed[1]; u.z = packed[2]; u.w = packed[3];
  wfrag[tid] = u;
}

// ---------------------------------------------------------------------------
// Phase helper macros (h_ / nf2_ literals; named frags only -> registers).
// Identical to the verified R9 kernel.
// ---------------------------------------------------------------------------

// q/k: swapped orientation. D[o][t]: col t = 16m+lr, rows o = nf*16+4lq+r.
#define QK_STORE(fA_, fB_, nf2_, h_, bp_, bsc_, dst_) do {                    \
  const int nf = 2 * (h_) + (nf2_);                                           \
  float4 b4 = *(const float4*)&(bp_)[g * 64 + nf * 16 + 4 * lq];              \
  _Pragma("unroll")                                                           \
  for (int m = 0; m < 2; ++m) {                                               \
    f32x4 a1 = {b4.x * (bsc_), b4.y * (bsc_), b4.z * (bsc_), b4.w * (bsc_)};  \
    a1 = __builtin_amdgcn_mfma_f32_16x16x32_bf16((fA_).v, afr[m][0], a1, 0, 0, 0); \
    a1 = __builtin_amdgcn_mfma_f32_16x16x32_bf16((fB_).v, afr[m][1], a1, 0, 0, 0); \
    uint2 w2; w2.x = pk2(a1[0], a1[1]); w2.y = pk2(a1[2], a1[3]);             \
    const int blk = (16 * (2 * (nf2_) + (lq >> 1)) + g) ^ (lr & 7);           \
    *(uint2*)&(dst_)[(16 * m + lr) * 512 + blk * 8 + 4 * (lq & 1)] = w2;      \
  }                                                                           \
} while (0)

// v: original orientation. D[t][o]: rows t = 16m+4lq+r, col d_h = nf2*16+lr;
// stream pos encodes (f=g, d): pos = 64*(g>>2) + 4*d + (g&3).
#define V_STORE(fA_, fB_, nf2_, h_) do {                                      \
  const int nf = 2 * (h_) + (nf2_);                                           \
  const float bias = bv[g * 64 + nf * 16 + lr];                               \
  const int L = 16 * (g >> 2) + lr;                                           \
  const int jj = g & 3;                                                       \
  _Pragma("unroll")                                                           \
  for (int m = 0; m < 2; ++m) {                                               \
    f32x4 a1 = {bias, bias, bias, bias};                                      \
    a1 = __builtin_amdgcn_mfma_f32_16x16x32_bf16(afr[m][0], (fA_).v, a1, 0, 0, 0); \
    a1 = __builtin_amdgcn_mfma_f32_16x16x32_bf16(afr[m][1], (fB_).v, a1, 0, 0, 0); \
    _Pragma("unroll")                                                         \
    for (int r = 0; r < 4; ++r)                                               \
      s_v[((16 * m + 4 * lq + r) * 2 + (nf2_)) * 256 + L * 4 + jj] = f2bf(a1[r]); \
  }                                                                           \
} while (0)

#define PH1(h_) do {                                                          \
  FragCast q0a, q0b, q1a, q1b, k0a, k0b, k1a, k1b, v0a, v0b, v1a, v1b;        \
  q0a.u4 = wfrag[(((0 * 16 + g) * 2 + 0) * 4 + 2 * (h_)    ) * 64 + lane];    \
  q0b.u4 = wfrag[(((0 * 16 + g) * 2 + 1) * 4 + 2 * (h_)    ) * 64 + lane];    \
  q1a.u4 = wfrag[(((0 * 16 + g) * 2 + 0) * 4 + 2 * (h_) + 1) * 64 + lane];    \
  q1b.u4 = wfrag[(((0 * 16 + g) * 2 + 1) * 4 + 2 * (h_) + 1) * 64 + lane];    \
  k0a.u4 = wfrag[(((1 * 16 + g) * 2 + 0) * 4 + 2 * (h_)    ) * 64 + lane];    \
  k0b.u4 = wfrag[(((1 * 16 + g) * 2 + 1) * 4 + 2 * (h_)    ) * 64 + lane];    \
  k1a.u4 = wfrag[(((1 * 16 + g) * 2 + 0) * 4 + 2 * (h_) + 1) * 64 + lane];    \
  k1b.u4 = wfrag[(((1 * 16 + g) * 2 + 1) * 4 + 2 * (h_) + 1) * 64 + lane];    \
  v0a.u4 = wfrag[(((2 * 16 + g) * 2 + 0) * 4 + 2 * (h_)    ) * 64 + lane];    \
  v0b.u4 = wfrag[(((2 * 16 + g) * 2 + 1) * 4 + 2 * (h_)    ) * 64 + lane];    \
  v1a.u4 = wfrag[(((2 * 16 + g) * 2 + 0) * 4 + 2 * (h_) + 1) * 64 + lane];    \
  v1b.u4 = wfrag[(((2 * 16 + g) * 2 + 1) * 4 + 2 * (h_) + 1) * 64 + lane];    \
  QK_STORE(q0a, q0b, 0, h_, bq, QSCALE, s_q);                                 \
  QK_STORE(q1a, q1b, 1, h_, bq, QSCALE, s_q);                                 \
  QK_STORE(k0a, k0b, 0, h_, bk, 1.0f,   s_k);                                 \
  QK_STORE(k1a, k1b, 1, h_, bk, 1.0f,   s_k);                                 \
  V_STORE(v0a, v0b, 0, h_);                                                   \
  V_STORE(v1a, v1b, 1, h_);                                                   \
} while (0)

// PH2: QK^T + softmax + PV for t = g and t = g+16 of the current head.
#define PH2(ATT_) do {                                                        \
  _Pragma("unroll")                                                           \
  for (int tt = 0; tt < 2; ++tt) {                                            \
    const int t = g + 16 * tt;                                                \
    f32x4 zero = {0.f, 0.f, 0.f, 0.f};                                        \
    FragCast qa, ka;                                                          \
    const int blk = lane ^ (t & 7);                                           \
    qa.u4 = *(const uint4*)&s_q[t * 512 + blk * 8];                           \
    ka.u4 = *(const uint4*)&s_k[t * 512 + blk * 8];                           \
    /* D[f][g]: col g=lr, rows f=4lq+r (K=32 = full head dim) */              \
    f32x4 sc4 = __builtin_amdgcn_mfma_f32_16x16x32_bf16(ka.v, qa.v, zero, 0, 0, 0); \
    float m = fmaxf(fmaxf(sc4[0], sc4[1]), fmaxf(sc4[2], sc4[3]));            \
    m = fmaxf(m, __shfl_xor(m, 16));                                          \
    m = fmaxf(m, __shfl_xor(m, 32));                                          \
    float p0 = exp2f((sc4[0] - m) * LOG2E);                                   \
    float p1 = exp2f((sc4[1] - m) * LOG2E);                                   \
    float p2 = exp2f((sc4[2] - m) * LOG2E);                                   \
    float p3 = exp2f((sc4[3] - m) * LOG2E);                                   \
    float s = p0 + p1 + p2 + p3;                                              \
    s += __shfl_xor(s, 16);                                                   \
    s += __shfl_xor(s, 32);                                                   \
    const float inv = __fdividef(1.0f, s);                                    \
    FragCast pa;               /* P[g=lr][f=4lq+jj] at slots jj 0..3 */       \
    pa.u[0] = pk2(p0 * inv, p1 * inv);                                        \
    pa.u[1] = pk2(p2 * inv, p3 * inv);                                        \
    pa.u[2] = 0; pa.u[3] = 0;                                                 \
    FragCast va0, va1;         /* V[f=4lq+jj][d=nf*16+lr] at slots jj 0..3 */ \
    va0.u2[0] = *(const uint2*)&s_v[(t * 2 + 0) * 256 + lane * 4];            \
    va0.u[2] = 0; va0.u[3] = 0;                                               \
    va1.u2[0] = *(const uint2*)&s_v[(t * 2 + 1) * 256 + lane * 4];            \
    va1.u[2] = 0; va1.u[3] = 0;                                               \
    /* D[d][g]: col g=lr, rows d=nf*16+4lq+r */                               \
    f32x4 oo0 = __builtin_amdgcn_mfma_f32_16x16x32_bf16(va0.v, pa.v, zero, 0, 0, 0); \
    f32x4 oo1 = __builtin_amdgcn_mfma_f32_16x16x32_bf16(va1.v, pa.v, zero, 0, 0, 0); \
    uint2 w20; w20.x = pk2(oo0[0], oo0[1]); w20.y = pk2(oo0[2], oo0[3]);      \
    const int ab0 = (16 * (0 + (lq >> 1)) + lr) ^ (t & 7);                    \
    *(uint2*)&(ATT_)[t * 512 + ab0 * 8 + 4 * (lq & 1)] = w20;                 \
    uint2 w21; w21.x = pk2(oo1[0], oo1[1]); w21.y = pk2(oo1[2], oo1[3]);      \
    const int ab1 = (16 * (2 + (lq >> 1)) + lr) ^ (t & 7);                    \
    *(uint2*)&(ATT_)[t * 512 + ab1 * 8 + 4 * (lq & 1)] = w21;                 \
  }                                                                           \
} while (0)

#define LOADF() do {                                                          \
  f0n0.u4 = wfrag[(((3 * 16 + g) * 2 + 0) * 4 + 0) * 64 + lane];              \
  f0n1.u4 = wfrag[(((3 * 16 + g) * 2 + 0) * 4 + 1) * 64 + lane];              \
  f0n2.u4 = wfrag[(((3 * 16 + g) * 2 + 0) * 4 + 2) * 64 + lane];              \
  f0n3.u4 = wfrag[(((3 * 16 + g) * 2 + 0) * 4 + 3) * 64 + lane];              \
  f1n0.u4 = wfrag[(((3 * 16 + g) * 2 + 1) * 4 + 0) * 64 + lane];              \
  f1n1.u4 = wfrag[(((3 * 16 + g) * 2 + 1) * 4 + 1) * 64 + lane];              \
  f1n2.u4 = wfrag[(((3 * 16 + g) * 2 + 1) * 4 + 2) * 64 + lane];              \
  f1n3.u4 = wfrag[(((3 * 16 + g) * 2 + 1) * 4 + 3) * 64 + lane];              \
} while (0)

#define PH3_NF(f0_, f1_, nf_, m_, aa0_, aa1_) do {                            \
  float4 b4 = *(const float4*)&bfb[g * 64 + (nf_) * 16 + 4 * lq];             \
  f32x4 a1 = {b4.x, b4.y, b4.z, b4.w};                                        \
  a1 = __builtin_amdgcn_mfma_f32_16x16x32_bf16((f0_).v, (aa0_).v, a1, 0, 0, 0); \
  a1 = __builtin_amdgcn_mfma_f32_16x16x32_bf16((f1_).v, (aa1_).v, a1, 0, 0, 0); \
  float4 o4; o4.x = a1[0]; o4.y = a1[1]; o4.z = a1[2]; o4.w = a1[3];          \
  *(float4*)&out[(tok0 + 16 * (m_) + lr) * DM + g * 64 + (nf_) * 16 + 4 * lq] = o4; \
} while (0)

#define PH3() do {                                                            \
  const int blk3 = (16 * lq + g) ^ (lr & 7);                                  \
  _Pragma("unroll")                                                           \
  for (int m = 0; m < 2; ++m) {                                               \
    FragCast aa0, aa1;         /* att[t=16m+lr][g][d_h=8lq+j], per head */    \
    aa0.u4 = *(const uint4*)&s_a0[(16 * m + lr) * 512 + blk3 * 8];            \
    aa1.u4 = *(const uint4*)&s_a1[(16 * m + lr) * 512 + blk3 * 8];            \
    PH3_NF(f0n0, f1n0, 0, m, aa0, aa1);                                       \
    PH3_NF(f0n1, f1n1, 1, m, aa0, aa1);                                       \
    PH3_NF(f0n2, f1n2, 2, m, aa0, aa1);                                       \
    PH3_NF(f0n3, f1n3, 3, m, aa0, aa1);                                       \
  }                                                                           \
} while (0)

// x half-tile load (4 named float4) and pack into afr[m_][*].
#define XLOAD_HALF(tokrow_) do {                                              \
  const float* xr = x + (tokrow_) * DM + g * 64;                              \
  y0 = *(const float4*)(xr + 8 * lq);                                         \
  y1 = *(const float4*)(xr + 8 * lq + 4);                                     \
  y2 = *(const float4*)(xr + 32 + 8 * lq);                                    \
  y3 = *(const float4*)(xr + 32 + 8 * lq + 4);                                \
} while (0)

#define XPACK_HALF(m_) do {                                                   \
  afr[m_][0] = pack8(y0, y1);                                                 \
  afr[m_][1] = pack8(y2, y3);                                                 \
} while (0)

// ---------------------------------------------------------------------------
__global__ __launch_bounds__(1024)
void fused_pers32(const float* __restrict__ x,
                  const float* __restrict__ bq, const float* __restrict__ bk,
                  const float* __restrict__ bv, const float* __restrict__ bfb,
                  const uint4* __restrict__ wfrag,
                  float* __restrict__ out) {
  // Dynamic LDS, 160KB: five 32KB buffers.
  // q/k/a0/a1: [t(32)][blk(64)] x 16B, blk key ^(t&7).
  // v: [(t*2+nf2)][256 shorts] stream, pos = 64*(g>>2)+4*d+(g&3).
  extern __shared__ __align__(16) unsigned short sm[];
  unsigned short* const s_q  = sm;
  unsigned short* const s_k  = sm + 16384;
  unsigned short* const s_v  = sm + 32768;
  unsigned short* const s_a0 = sm + 49152;
  unsigned short* const s_a1 = sm + 65536;

  const int tid  = threadIdx.x;
  const int g    = tid >> 6;      // 16 waves: wave = g (PH1/PH3), t-base (PH2)
  const int lane = tid & 63;
  const int lr   = lane & 15;
  const int lq   = lane >> 4;
  const long base = (long)blockIdx.x * (NT * TILE);

  bf16x8 afr[2][2];               // current tile's x fragments
  float4 y0, y1, y2, y3;          // transient x staging (one half-tile)
  FragCast f0n0, f0n1, f0n2, f0n3, f1n0, f1n1, f1n2, f1n3;  // PH3 weights

  // prologue: load tile 0's x
  XLOAD_HALF(base + lr);       XPACK_HALF(0);
  XLOAD_HALF(base + 16 + lr);  XPACK_HALF(1);

  for (int it = 0; it < NT; ++it) {
    const long tok0 = base + (long)it * TILE;

    PH1(0);
    __syncthreads();                  // B1
    PH2(s_a0);
    __syncthreads();                  // B2
    PH1(1);
    __syncthreads();                  // B3
    LOADF();                          // f-frags hide under PH2(1)
    PH2(s_a1);
    __syncthreads();                  // B4

    // tail span: next-tile x prefetch interleaved with PH3+stores.
    // Loads for m0 issue first; PH3's 16 MFMAs + 8 stores hide their latency.
    if (it + 1 < NT) XLOAD_HALF(tok0 + TILE + lr);
    PH3();
    if (it + 1 < NT) {
      XPACK_HALF(0);
      XLOAD_HALF(tok0 + TILE + 16 + lr);
      XPACK_HALF(1);
    }
    // loop-back to PH1(0): writes s_q/k/v (last read before B4); next PH2's
    // a0/a1 writes are separated from this PH3's reads by next B1/B2.
  }
}

// ---------------------------------------------------------------------------
extern "C" void kernel_launch(void* const* d_in, const int* in_sizes, int n_in,
                              void* d_out, int out_size, void* d_ws, size_t ws_size,
                              hipStream_t stream) {
  const float* x   = (const float*)d_in[0];
  const float* wq  = (const float*)d_in[1];
  const float* bq_ = (const float*)d_in[2];
  const float* wk  = (const float*)d_in[3];
  const float* bk_ = (const float*)d_in[4];
  const float* wv  = (const float*)d_in[5];
  const float* bv_ = (const float*)d_in[6];
  const float* wf  = (const float*)d_in[7];
  const float* bf_ = (const float*)d_in[8];
  (void)in_sizes; (void)n_in; (void)out_size; (void)ws_size;

  uint4* wfrag = (uint4*)d_ws;   // 4*16*2*4*64 frags * 16B = 512 KiB

  const int lds_bytes = 5 * 32 * 1024;   // 160 KB
  hipFuncSetAttribute(reinterpret_cast<const void*>(fused_pers32),
                      hipFuncAttributeMaxDynamicSharedMemorySize, lds_bytes);

  build_wfrag<<<128, 256, 0, stream>>>(wq, wk, wv, wf, wfrag);
  fused_pers32<<<NTOK / (NT * TILE), 1024, lds_bytes, stream>>>(
      x, bq_, bk_, bv_, bf_, wfrag, (float*)d_out);
}

// Round 14
// 259.688 us; speedup vs baseline: 3.6102x; 1.3329x over previous
//
#include <hip/hip_runtime.h>
#include <hip/hip_bf16.h>
#include <stdint.h>

// GroupCommunication fused: 65536 tok x 1024 ch; 16 blocks x 64; 2 heads x 32.
// R14: R9's light-chain structure (1 g per wave, batched weight loads,
// swapped-MFMA layouts) at TT=16 so LDS = 5 x 16KB = 80KB STATIC ->
// exactly 2 WGs/CU = two independent barrier domains (the untested matrix
// cell; R10's attempt died of a forced (1024,8) VGPR cap, not the idea).
// PH3 runs ONCE over both att buffers -> no persistent accumulators; the
// cross-barrier live set is ~afr(8)+f-frags(32 spanning B4 only) ~= R9's 52,
// under the empirical 64-VGPR wall (R5/R7/R10/R11/R12/R13 all spilled
// above it). Default __launch_bounds__(1024).
// Schedule: PH1(0) |B1| PH2(0)->a0 |B2| PH1(1) |B3| LOADF+PH2(1)->a1 |B4|
//           PH3+store.  Grid 4096 (16 tokens per WG).

typedef __attribute__((ext_vector_type(8))) short bf16x8;
typedef __attribute__((ext_vector_type(4))) float f32x4;

#define NTOK   65536
#define DM     1024
#define TT     16
#define QSCALE 0.17677669529663687f    // 32^-0.5
#define LOG2E  1.4426950408889634f

static __device__ __forceinline__ unsigned short f2bf(float f) {
  union { __hip_bfloat16 h; unsigned short s; } cv;
  cv.h = __float2bfloat16(f);          // RNE
  return cv.s;
}

static __device__ __forceinline__ unsigned int pk2(float a, float b) {
  return (unsigned int)f2bf(a) | ((unsigned int)f2bf(b) << 16);
}

static __device__ __forceinline__ bf16x8 pack8(float4 a, float4 b) {
  bf16x8 r;
  r[0] = (short)f2bf(a.x); r[1] = (short)f2bf(a.y);
  r[2] = (short)f2bf(a.z); r[3] = (short)f2bf(a.w);
  r[4] = (short)f2bf(b.x); r[5] = (short)f2bf(b.y);
  r[6] = (short)f2bf(b.z); r[7] = (short)f2bf(b.w);
  return r;
}

union FragCast { uint4 u4; bf16x8 v; uint2 u2[2]; unsigned int u[4]; };

// ---------------------------------------------------------------------------
// Prologue: pack wq(scaled),wk,wv,wf fp32 [g][i][o] -> bf16 fragment stream.
// frag elem j = W[k = kk*32 + 8*(lane>>4) + j][o = nf*16 + (lane&15)].
// A- and B-side consumers always use the identical (lane,j)->k map.
// ---------------------------------------------------------------------------
__global__ void build_wfrag(const float* __restrict__ wq, const float* __restrict__ wk,
                            const float* __restrict__ wv, const float* __restrict__ wf,
                            uint4* __restrict__ wfrag) {
  int tid = blockIdx.x * 256 + threadIdx.x;
  if (tid >= 4 * 16 * 2 * 4 * 64) return;
  int lane =  tid        & 63;
  int nf   = (tid >> 6)  & 3;
  int kk   = (tid >> 8)  & 1;
  int g    = (tid >> 9)  & 15;
  int mat  =  tid >> 13;
  const float* w = (mat == 0) ? wq : (mat == 1) ? wk : (mat == 2) ? wv : wf;
  float sc = (mat == 0) ? QSCALE : 1.0f;
  int o  = nf * 16 + (lane & 15);
  int kb = kk * 32 + 8 * (lane >> 4);
  unsigned int packed[4];
#pragma unroll
  for (int jj = 0; jj < 4; ++jj) {
    unsigned short lo = f2bf(w[(g * 64 + kb + 2 * jj    ) * 64 + o] * sc);
    unsigned short hi = f2bf(w[(g * 64 + kb + 2 * jj + 1) * 64 + o] * sc);
    packed[jj] = (unsigned int)lo | ((unsigned int)hi << 16);
  }
  uint4 u; u.x = packed[0]; u.y = packed[1]; u.z = packed[2]; u.w = packed[3];
  wfrag[tid] = u;
}

// ---------------------------------------------------------------------------
// Phase helper macros (h_ / nf2_ literals; named frags only -> registers).
// Formulas = verified R9 kernel with the m/tt loops removed (single 16-token
// tile: token row = lr; PH2 token t = g).
// ---------------------------------------------------------------------------

// q/k: swapped orientation. D[o][t]: col t = lr, rows o = nf*16+4lq+r.
#define QK_STORE(fA_, fB_, nf2_, h_, bp_, bsc_, dst_) do {                    \
  const int nf = 2 * (h_) + (nf2_);                                           \
  float4 b4 = *(const float4*)&(bp_)[g * 64 + nf * 16 + 4 * lq];              \
  f32x4 a1 = {b4.x * (bsc_), b4.y * (bsc_), b4.z * (bsc_), b4.w * (bsc_)};    \
  a1 = __builtin_amdgcn_mfma_f32_16x16x32_bf16((fA_).v, afr0, a1, 0, 0, 0);   \
  a1 = __builtin_amdgcn_mfma_f32_16x16x32_bf16((fB_).v, afr1, a1, 0, 0, 0);   \
  uint2 w2; w2.x = pk2(a1[0], a1[1]); w2.y = pk2(a1[2], a1[3]);               \
  const int blk = (16 * (2 * (nf2_) + (lq >> 1)) + g) ^ (lr & 7);             \
  *(uint2*)&(dst_)[lr * 512 + blk * 8 + 4 * (lq & 1)] = w2;                   \
} while (0)

// v: original orientation. D[t][o]: rows t = 4lq+r, col d_h = nf2*16+lr;
// stream pos encodes (f=g, d): pos = 64*(g>>2) + 4*d + (g&3).
#define V_STORE(fA_, fB_, nf2_, h_) do {                                      \
  const int nf = 2 * (h_) + (nf2_);                                           \
  const float bias = bv[g * 64 + nf * 16 + lr];                               \
  const int L = 16 * (g >> 2) + lr;                                           \
  const int jj = g & 3;                                                       \
  f32x4 a1 = {bias, bias, bias, bias};                                        \
  a1 = __builtin_amdgcn_mfma_f32_16x16x32_bf16(afr0, (fA_).v, a1, 0, 0, 0);   \
  a1 = __builtin_amdgcn_mfma_f32_16x16x32_bf16(afr1, (fB_).v, a1, 0, 0, 0);   \
  _Pragma("unroll")                                                           \
  for (int r = 0; r < 4; ++r)                                                 \
    s_v[((4 * lq + r) * 2 + (nf2_)) * 256 + L * 4 + jj] = f2bf(a1[r]);        \
} while (0)

#define PH1(h_) do {                                                          \
  FragCast q0a, q0b, q1a, q1b, k0a, k0b, k1a, k1b, v0a, v0b, v1a, v1b;        \
  q0a.u4 = wfrag[(((0 * 16 + g) * 2 + 0) * 4 + 2 * (h_)    ) * 64 + lane];    \
  q0b.u4 = wfrag[(((0 * 16 + g) * 2 + 1) * 4 + 2 * (h_)    ) * 64 + lane];    \
  q1a.u4 = wfrag[(((0 * 16 + g) * 2 + 0) * 4 + 2 * (h_) + 1) * 64 + lane];    \
  q1b.u4 = wfrag[(((0 * 16 + g) * 2 + 1) * 4 + 2 * (h_) + 1) * 64 + lane];    \
  k0a.u4 = wfrag[(((1 * 16 + g) * 2 + 0) * 4 + 2 * (h_)    ) * 64 + lane];    \
  k0b.u4 = wfrag[(((1 * 16 + g) * 2 + 1) * 4 + 2 * (h_)    ) * 64 + lane];    \
  k1a.u4 = wfrag[(((1 * 16 + g) * 2 + 0) * 4 + 2 * (h_) + 1) * 64 + lane];    \
  k1b.u4 = wfrag[(((1 * 16 + g) * 2 + 1) * 4 + 2 * (h_) + 1) * 64 + lane];    \
  v0a.u4 = wfrag[(((2 * 16 + g) * 2 + 0) * 4 + 2 * (h_)    ) * 64 + lane];    \
  v0b.u4 = wfrag[(((2 * 16 + g) * 2 + 1) * 4 + 2 * (h_)    ) * 64 + lane];    \
  v1a.u4 = wfrag[(((2 * 16 + g) * 2 + 0) * 4 + 2 * (h_) + 1) * 64 + lane];    \
  v1b.u4 = wfrag[(((2 * 16 + g) * 2 + 1) * 4 + 2 * (h_) + 1) * 64 + lane];    \
  QK_STORE(q0a, q0b, 0, h_, bq, QSCALE, s_q);                                 \
  QK_STORE(q1a, q1b, 1, h_, bq, QSCALE, s_q);                                 \
  QK_STORE(k0a, k0b, 0, h_, bk, 1.0f,   s_k);                                 \
  QK_STORE(k1a, k1b, 1, h_, bk, 1.0f,   s_k);                                 \
  V_STORE(v0a, v0b, 0, h_);                                                   \
  V_STORE(v1a, v1b, 1, h_);                                                   \
} while (0)

// PH2: QK^T + softmax + PV for token t = g (wave id), current head.
#define PH2(ATT_) do {                                                        \
  const int t = g;                                                            \
  f32x4 zero = {0.f, 0.f, 0.f, 0.f};                                          \
  FragCast qa, ka;                                                            \
  const int blk = lane ^ (t & 7);                                             \
  qa.u4 = *(const uint4*)&s_q[t * 512 + blk * 8];                             \
  ka.u4 = *(const uint4*)&s_k[t * 512 + blk * 8];                             \
  /* D[f][g]: col g=lr, rows f=4lq+r (K=32 = full head dim) */                \
  f32x4 sc4 = __builtin_amdgcn_mfma_f32_16x16x32_bf16(ka.v, qa.v, zero, 0, 0, 0); \
  float m = fmaxf(fmaxf(sc4[0], sc4[1]), fmaxf(sc4[2], sc4[3]));              \
  m = fmaxf(m, __shfl_xor(m, 16));                                            \
  m = fmaxf(m, __shfl_xor(m, 32));                                            \
  float p0 = exp2f((sc4[0] - m) * LOG2E);                                     \
  float p1 = exp2f((sc4[1] - m) * LOG2E);                                     \
  float p2 = exp2f((sc4[2] - m) * LOG2E);                                     \
  float p3 = exp2f((sc4[3] - m) * LOG2E);                                     \
  float s = p0 + p1 + p2 + p3;                                                \
  s += __shfl_xor(s, 16);                                                     \
  s += __shfl_xor(s, 32);                                                     \
  const float inv = __fdividef(1.0f, s);                                      \
  FragCast pa;                 /* P[g=lr][f=4lq+jj] at slots jj 0..3 */       \
  pa.u[0] = pk2(p0 * inv, p1 * inv);                                          \
  pa.u[1] = pk2(p2 * inv, p3 * inv);                                          \
  pa.u[2] = 0; pa.u[3] = 0;                                                   \
  FragCast va0, va1;           /* V[f=4lq+jj][d=nf*16+lr] at slots jj 0..3 */ \
  va0.u2[0] = *(const uint2*)&s_v[(t * 2 + 0) * 256 + lane * 4];              \
  va0.u[2] = 0; va0.u[3] = 0;                                                 \
  va1.u2[0] = *(const uint2*)&s_v[(t * 2 + 1) * 256 + lane * 4];              \
  va1.u[2] = 0; va1.u[3] = 0;                                                 \
  /* D[d][g]: col g=lr, rows d=nf*16+4lq+r */                                 \
  f32x4 oo0 = __builtin_amdgcn_mfma_f32_16x16x32_bf16(va0.v, pa.v, zero, 0, 0, 0); \
  f32x4 oo1 = __builtin_amdgcn_mfma_f32_16x16x32_bf16(va1.v, pa.v, zero, 0, 0, 0); \
  uint2 w20; w20.x = pk2(oo0[0], oo0[1]); w20.y = pk2(oo0[2], oo0[3]);        \
  const int ab0 = (16 * (0 + (lq >> 1)) + lr) ^ (t & 7);                      \
  *(uint2*)&(ATT_)[t * 512 + ab0 * 8 + 4 * (lq & 1)] = w20;                   \
  uint2 w21; w21.x = pk2(oo1[0], oo1[1]); w21.y = pk2(oo1[2], oo1[3]);        \
  const int ab1 = (16 * (2 + (lq >> 1)) + lr) ^ (t & 7);                      \
  *(uint2*)&(ATT_)[t * 512 + ab1 * 8 + 4 * (lq & 1)] = w21;                   \
} while (0)

#define LOADF() do {                                                          \
  f0n0.u4 = wfrag[(((3 * 16 + g) * 2 + 0) * 4 + 0) * 64 + lane];              \
  f0n1.u4 = wfrag[(((3 * 16 + g) * 2 + 0) * 4 + 1) * 64 + lane];              \
  f0n2.u4 = wfrag[(((3 * 16 + g) * 2 + 0) * 4 + 2) * 64 + lane];              \
  f0n3.u4 = wfrag[(((3 * 16 + g) * 2 + 0) * 4 + 3) * 64 + lane];              \
  f1n0.u4 = wfrag[(((3 * 16 + g) * 2 + 1) * 4 + 0) * 64 + lane];              \
  f1n1.u4 = wfrag[(((3 * 16 + g) * 2 + 1) * 4 + 1) * 64 + lane];              \
  f1n2.u4 = wfrag[(((3 * 16 + g) * 2 + 1) * 4 + 2) * 64 + lane];              \
  f1n3.u4 = wfrag[(((3 * 16 + g) * 2 + 1) * 4 + 3) * 64 + lane];              \
} while (0)

#define PH3_NF(f0_, f1_, nf_, aa0_, aa1_) do {                                \
  float4 b4 = *(const float4*)&bfb[g * 64 + (nf_) * 16 + 4 * lq];             \
  f32x4 a1 = {b4.x, b4.y, b4.z, b4.w};                                        \
  a1 = __builtin_amdgcn_mfma_f32_16x16x32_bf16((f0_).v, (aa0_).v, a1, 0, 0, 0); \
  a1 = __builtin_amdgcn_mfma_f32_16x16x32_bf16((f1_).v, (aa1_).v, a1, 0, 0, 0); \
  float4 o4; o4.x = a1[0]; o4.y = a1[1]; o4.z = a1[2]; o4.w = a1[3];          \
  *(float4*)&out[(tok0 + lr) * DM + g * 64 + (nf_) * 16 + 4 * lq] = o4;       \
} while (0)

#define PH3() do {                                                            \
  const int blk3 = (16 * lq + g) ^ (lr & 7);                                  \
  FragCast aa0, aa1;           /* att[t=lr][g][d_h=8lq+j], per head */        \
  aa0.u4 = *(const uint4*)&s_a0[lr * 512 + blk3 * 8];                         \
  aa1.u4 = *(const uint4*)&s_a1[lr * 512 + blk3 * 8];                         \
  PH3_NF(f0n0, f1n0, 0, aa0, aa1);                                            \
  PH3_NF(f0n1, f1n1, 1, aa0, aa1);                                            \
  PH3_NF(f0n2, f1n2, 2, aa0, aa1);                                            \
  PH3_NF(f0n3, f1n3, 3, aa0, aa1);                                            \
} while (0)

// ---------------------------------------------------------------------------
__global__ __launch_bounds__(1024)
void fused_gc16b(const float* __restrict__ x,
                 const float* __restrict__ bq, const float* __restrict__ bk,
                 const float* __restrict__ bv, const float* __restrict__ bfb,
                 const uint4* __restrict__ wfrag,
                 float* __restrict__ out) {
  // STATIC 80KB LDS -> exactly 2 WGs/CU (visible bound -> sane regalloc).
  // q/k/a0/a1: [t(16)][blk(64)] x 16B, blk key ^(t&7).  16KB each.
  // v: [(t*2+nf2)][256 shorts] stream, pos = 64*(g>>2)+4*d+(g&3).  16KB.
  __shared__ __align__(16) unsigned short s_q [16 * 512];
  __shared__ __align__(16) unsigned short s_k [16 * 512];
  __shared__ __align__(16) unsigned short s_v [16 * 512];
  __shared__ __align__(16) unsigned short s_a0[16 * 512];
  __shared__ __align__(16) unsigned short s_a1[16 * 512];

  const int tid  = threadIdx.x;
  const int g    = tid >> 6;      // 16 waves: wave = g (PH1/PH3), token t (PH2)
  const int lane = tid & 63;
  const int lr   = lane & 15;
  const int lq   = lane >> 4;
  const long tok0 = (long)blockIdx.x * TT;

  // x fragments: token row lr, channel block g
  bf16x8 afr0, afr1;
  {
    const float* xr = x + (tok0 + lr) * DM + g * 64;
    afr0 = pack8(*(const float4*)(xr + 8 * lq), *(const float4*)(xr + 8 * lq + 4));
    afr1 = pack8(*(const float4*)(xr + 32 + 8 * lq), *(const float4*)(xr + 32 + 8 * lq + 4));
  }

  FragCast f0n0, f0n1, f0n2, f0n3, f1n0, f1n1, f1n2, f1n3;  // PH3 weights

  PH1(0);
  __syncthreads();                // B1
  PH2(s_a0);
  __syncthreads();                // B2
  PH1(1);
  __syncthreads();                // B3
  LOADF();                        // f-frags hide under PH2(1)
  PH2(s_a1);
  __syncthreads();                // B4
  PH3();
}

// ---------------------------------------------------------------------------
extern "C" void kernel_launch(void* const* d_in, const int* in_sizes, int n_in,
                              void* d_out, int out_size, void* d_ws, size_t ws_size,
                              hipStream_t stream) {
  const float* x   = (const float*)d_in[0];
  const float* wq  = (const float*)d_in[1];
  const float* bq_ = (const float*)d_in[2];
  const float* wk  = (const float*)d_in[3];
  const float* bk_ = (const float*)d_in[4];
  const float* wv  = (const float*)d_in[5];
  const float* bv_ = (const float*)d_in[6];
  const float* wf  = (const float*)d_in[7];
  const float* bf_ = (const float*)d_in[8];
  (void)in_sizes; (void)n_in; (void)out_size; (void)ws_size;

  uint4* wfrag = (uint4*)d_ws;   // 4*16*2*4*64 frags * 16B = 512 KiB

  build_wfrag<<<128, 256, 0, stream>>>(wq, wk, wv, wf, wfrag);
  fused_gc16b<<<NTOK / TT, 1024, 0, stream>>>(x, bq_, bk_, bv_, bf_, wfrag,
                                              (float*)d_out);
}

// Round 15
// 235.481 us; speedup vs baseline: 3.9813x; 1.1028x over previous
//
#include <hip/hip_runtime.h>
#include <hip/hip_bf16.h>
#include <stdint.h>

// GroupCommunication fused: 65536 tok x 1024 ch; 16 blocks x 64; 2 heads x 32.
// R15 = R10's schedule (TT=16, 1024 thr, 1 g per wave, head-sequential PH3
// with reg accumulators, 4 buffers x 16KB = 64KB STATIC LDS -> 2 WGs/CU with
// 32KB slack) with the poison removed: DEFAULT __launch_bounds__(1024).
// R10's 239us was the forced (1024,8) -> VGPR 32 + spill; R14 proved the
// light-chain body naturally allocates 36 VGPR. Live set here ~52-60 <= 64
// -> 8 waves/SIMD -> both WGs get slots (the first clean test of
// light-chain x 2 barrier domains; R14's 80KB x2 = exactly 160KB didn't
// co-schedule, occupancy stayed 49%).
// Schedule: PH1(0) |B1| PH2->att |B2| accinit+PH3(0)+PH1(1) |B3| PH2->att'
// ... wait: PH2(1) overwrites s_att only after B3, and PH3(0) read it before
// B3 -> safe. |B4| PH3(1)+store.

typedef __attribute__((ext_vector_type(8))) short bf16x8;
typedef __attribute__((ext_vector_type(4))) float f32x4;

#define NTOK   65536
#define DM     1024
#define TT     16
#define QSCALE 0.17677669529663687f    // 32^-0.5
#define LOG2E  1.4426950408889634f

static __device__ __forceinline__ unsigned short f2bf(float f) {
  union { __hip_bfloat16 h; unsigned short s; } cv;
  cv.h = __float2bfloat16(f);          // RNE
  return cv.s;
}

static __device__ __forceinline__ unsigned int pk2(float a, float b) {
  return (unsigned int)f2bf(a) | ((unsigned int)f2bf(b) << 16);
}

static __device__ __forceinline__ bf16x8 pack8(float4 a, float4 b) {
  bf16x8 r;
  r[0] = (short)f2bf(a.x); r[1] = (short)f2bf(a.y);
  r[2] = (short)f2bf(a.z); r[3] = (short)f2bf(a.w);
  r[4] = (short)f2bf(b.x); r[5] = (short)f2bf(b.y);
  r[6] = (short)f2bf(b.z); r[7] = (short)f2bf(b.w);
  return r;
}

union FragCast { uint4 u4; bf16x8 v; uint2 u2[2]; unsigned int u[4]; };

// ---------------------------------------------------------------------------
// Prologue: pack wq(scaled),wk,wv,wf fp32 [g][i][o] -> bf16 fragment stream.
// frag elem j = W[k = kk*32 + 8*(lane>>4) + j][o = nf*16 + (lane&15)].
// A- and B-side consumers always use the identical (lane,j)->k map.
// ---------------------------------------------------------------------------
__global__ void build_wfrag(const float* __restrict__ wq, const float* __restrict__ wk,
                            const float* __restrict__ wv, const float* __restrict__ wf,
                            uint4* __restrict__ wfrag) {
  int tid = blockIdx.x * 256 + threadIdx.x;
  if (tid >= 4 * 16 * 2 * 4 * 64) return;
  int lane =  tid        & 63;
  int nf   = (tid >> 6)  & 3;
  int kk   = (tid >> 8)  & 1;
  int g    = (tid >> 9)  & 15;
  int mat  =  tid >> 13;
  const float* w = (mat == 0) ? wq : (mat == 1) ? wk : (mat == 2) ? wv : wf;
  float sc = (mat == 0) ? QSCALE : 1.0f;
  int o  = nf * 16 + (lane & 15);
  int kb = kk * 32 + 8 * (lane >> 4);
  unsigned int packed[4];
#pragma unroll
  for (int jj = 0; jj < 4; ++jj) {
    unsigned short lo = f2bf(w[(g * 64 + kb + 2 * jj    ) * 64 + o] * sc);
    unsigned short hi = f2bf(w[(g * 64 + kb + 2 * jj + 1) * 64 + o] * sc);
    packed[jj] = (unsigned int)lo | ((unsigned int)hi << 16);
  }
  uint4 u; u.x = packed[0]; u.y = packed[1]; u.z = packed[2]; u.w = packed[3];
  wfrag[tid] = u;
}

// ---------------------------------------------------------------------------
// Phase macros (h_/nf2_ literals; named frags only -> registers).
// Formulas identical to the verified R9/R14 kernels (single 16-token tile).
// ---------------------------------------------------------------------------

// q/k: swapped orientation. D[o][t]: col t = lr, rows o = nf*16+4lq+r.
#define QK_ONE(fA_, fB_, nf2_, h_, bp_, bsc_, dst_) do {                      \
  const int nf = 2 * (h_) + (nf2_);                                           \
  float4 b4 = *(const float4*)&(bp_)[g * 64 + nf * 16 + 4 * lq];              \
  f32x4 a1 = {b4.x * (bsc_), b4.y * (bsc_), b4.z * (bsc_), b4.w * (bsc_)};    \
  a1 = __builtin_amdgcn_mfma_f32_16x16x32_bf16((fA_).v, afr0, a1, 0, 0, 0);   \
  a1 = __builtin_amdgcn_mfma_f32_16x16x32_bf16((fB_).v, afr1, a1, 0, 0, 0);   \
  uint2 w2; w2.x = pk2(a1[0], a1[1]); w2.y = pk2(a1[2], a1[3]);               \
  const int blk = (16 * (2 * (nf2_) + (lq >> 1)) + g) ^ (lr & 7);             \
  *(uint2*)&(dst_)[lr * 512 + blk * 8 + 4 * (lq & 1)] = w2;                   \
} while (0)

// v: original orientation. D[t][o]: rows t = 4lq+r, col d_h = nf2*16+lr;
// stream pos encodes (f=g, d): pos = 64*(g>>2) + 4*d + (g&3).
#define V_ONE(fA_, fB_, nf2_, h_) do {                                        \
  const int nf = 2 * (h_) + (nf2_);                                           \
  const float bias = bv[g * 64 + nf * 16 + lr];                               \
  f32x4 a1 = {bias, bias, bias, bias};                                        \
  a1 = __builtin_amdgcn_mfma_f32_16x16x32_bf16(afr0, (fA_).v, a1, 0, 0, 0);   \
  a1 = __builtin_amdgcn_mfma_f32_16x16x32_bf16(afr1, (fB_).v, a1, 0, 0, 0);   \
  const int L = 16 * (g >> 2) + lr;                                           \
  const int jj = g & 3;                                                       \
  _Pragma("unroll")                                                           \
  for (int r = 0; r < 4; ++r)                                                 \
    s_v[((4 * lq + r) * 2 + (nf2_)) * 256 + L * 4 + jj] = f2bf(a1[r]);        \
} while (0)

#define PH1(h_) do {                                                          \
  {                                                                           \
    FragCast qa0, qb0, qa1, qb1;       /* q: [kk][nf2] */                     \
    qa0.u4 = wfrag[(((0 * 16 + g) * 2 + 0) * 4 + 2 * (h_)    ) * 64 + lane];  \
    qb0.u4 = wfrag[(((0 * 16 + g) * 2 + 0) * 4 + 2 * (h_) + 1) * 64 + lane];  \
    qa1.u4 = wfrag[(((0 * 16 + g) * 2 + 1) * 4 + 2 * (h_)    ) * 64 + lane];  \
    qb1.u4 = wfrag[(((0 * 16 + g) * 2 + 1) * 4 + 2 * (h_) + 1) * 64 + lane];  \
    QK_ONE(qa0, qa1, 0, h_, bq, QSCALE, s_q);                                 \
    QK_ONE(qb0, qb1, 1, h_, bq, QSCALE, s_q);                                 \
  }                                                                           \
  {                                                                           \
    FragCast ka0, kb0, ka1, kb1;                                              \
    ka0.u4 = wfrag[(((1 * 16 + g) * 2 + 0) * 4 + 2 * (h_)    ) * 64 + lane];  \
    kb0.u4 = wfrag[(((1 * 16 + g) * 2 + 0) * 4 + 2 * (h_) + 1) * 64 + lane];  \
    ka1.u4 = wfrag[(((1 * 16 + g) * 2 + 1) * 4 + 2 * (h_)    ) * 64 + lane];  \
    kb1.u4 = wfrag[(((1 * 16 + g) * 2 + 1) * 4 + 2 * (h_) + 1) * 64 + lane];  \
    QK_ONE(ka0, ka1, 0, h_, bk, 1.0f, s_k);                                   \
    QK_ONE(kb0, kb1, 1, h_, bk, 1.0f, s_k);                                   \
  }                                                                           \
  {                                                                           \
    FragCast va0, vb0, va1, vb1;                                              \
    va0.u4 = wfrag[(((2 * 16 + g) * 2 + 0) * 4 + 2 * (h_)    ) * 64 + lane];  \
    vb0.u4 = wfrag[(((2 * 16 + g) * 2 + 0) * 4 + 2 * (h_) + 1) * 64 + lane];  \
    va1.u4 = wfrag[(((2 * 16 + g) * 2 + 1) * 4 + 2 * (h_)    ) * 64 + lane];  \
    vb1.u4 = wfrag[(((2 * 16 + g) * 2 + 1) * 4 + 2 * (h_) + 1) * 64 + lane];  \
    V_ONE(va0, va1, 0, h_);                                                   \
    V_ONE(vb0, vb1, 1, h_);                                                   \
  }                                                                           \
} while (0)

// PH2: QK^T + softmax + PV for token t = g (wave id), current head.
#define PH2() do {                                                            \
  const int t = g;                                                            \
  f32x4 zero = {0.f, 0.f, 0.f, 0.f};                                          \
  FragCast qa, ka;                                                            \
  const int blk = lane ^ (t & 7);                                             \
  qa.u4 = *(const uint4*)&s_q[t * 512 + blk * 8];                             \
  ka.u4 = *(const uint4*)&s_k[t * 512 + blk * 8];                             \
  /* D[f][g]: col g=lr, rows f=4lq+r (K=32 = full head dim) */                \
  f32x4 sc4 = __builtin_amdgcn_mfma_f32_16x16x32_bf16(ka.v, qa.v, zero, 0, 0, 0); \
  float m = fmaxf(fmaxf(sc4[0], sc4[1]), fmaxf(sc4[2], sc4[3]));              \
  m = fmaxf(m, __shfl_xor(m, 16));                                            \
  m = fmaxf(m, __shfl_xor(m, 32));                                            \
  float p0 = exp2f((sc4[0] - m) * LOG2E);                                     \
  float p1 = exp2f((sc4[1] - m) * LOG2E);                                     \
  float p2 = exp2f((sc4[2] - m) * LOG2E);                                     \
  float p3 = exp2f((sc4[3] - m) * LOG2E);                                     \
  float s = p0 + p1 + p2 + p3;                                                \
  s += __shfl_xor(s, 16);                                                     \
  s += __shfl_xor(s, 32);                                                     \
  const float inv = __fdividef(1.0f, s);                                      \
  FragCast pa;                 /* P[g=lr][f=4lq+jj] at slots jj 0..3 */       \
  pa.u[0] = pk2(p0 * inv, p1 * inv);                                          \
  pa.u[1] = pk2(p2 * inv, p3 * inv);                                          \
  pa.u[2] = 0; pa.u[3] = 0;                                                   \
  FragCast va0, va1;           /* V[f=4lq+jj][d=nf*16+lr] at slots jj 0..3 */ \
  va0.u2[0] = *(const uint2*)&s_v[(t * 2 + 0) * 256 + lane * 4];              \
  va0.u[2] = 0; va0.u[3] = 0;                                                 \
  va1.u2[0] = *(const uint2*)&s_v[(t * 2 + 1) * 256 + lane * 4];              \
  va1.u[2] = 0; va1.u[3] = 0;                                                 \
  /* D[d][g]: col g=lr, rows d=nf*16+4lq+r */                                 \
  f32x4 oo0 = __builtin_amdgcn_mfma_f32_16x16x32_bf16(va0.v, pa.v, zero, 0, 0, 0); \
  f32x4 oo1 = __builtin_amdgcn_mfma_f32_16x16x32_bf16(va1.v, pa.v, zero, 0, 0, 0); \
  uint2 w20; w20.x = pk2(oo0[0], oo0[1]); w20.y = pk2(oo0[2], oo0[3]);        \
  const int ab0 = (16 * (0 + (lq >> 1)) + lr) ^ (t & 7);                      \
  *(uint2*)&s_att[t * 512 + ab0 * 8 + 4 * (lq & 1)] = w20;                    \
  uint2 w21; w21.x = pk2(oo1[0], oo1[1]); w21.y = pk2(oo1[2], oo1[3]);        \
  const int ab1 = (16 * (2 + (lq >> 1)) + lr) ^ (t & 7);                      \
  *(uint2*)&s_att[t * 512 + ab1 * 8 + 4 * (lq & 1)] = w21;                    \
} while (0)

// PH3(h): acc += wf(head h) x att. f-frags loaded at span start.
#define PH3(h_) do {                                                          \
  FragCast f0, f1, f2, f3;                                                    \
  f0.u4 = wfrag[(((3 * 16 + g) * 2 + (h_)) * 4 + 0) * 64 + lane];             \
  f1.u4 = wfrag[(((3 * 16 + g) * 2 + (h_)) * 4 + 1) * 64 + lane];             \
  f2.u4 = wfrag[(((3 * 16 + g) * 2 + (h_)) * 4 + 2) * 64 + lane];             \
  f3.u4 = wfrag[(((3 * 16 + g) * 2 + (h_)) * 4 + 3) * 64 + lane];             \
  const int blk3 = (16 * lq + g) ^ (lr & 7);                                  \
  FragCast aa;                 /* att[t=lr][g][d_h=8lq+j] -> B[k][t] */       \
  aa.u4 = *(const uint4*)&s_att[lr * 512 + blk3 * 8];                         \
  acc0 = __builtin_amdgcn_mfma_f32_16x16x32_bf16(f0.v, aa.v, acc0, 0, 0, 0);  \
  acc1 = __builtin_amdgcn_mfma_f32_16x16x32_bf16(f1.v, aa.v, acc1, 0, 0, 0);  \
  acc2 = __builtin_amdgcn_mfma_f32_16x16x32_bf16(f2.v, aa.v, acc2, 0, 0, 0);  \
  acc3 = __builtin_amdgcn_mfma_f32_16x16x32_bf16(f3.v, aa.v, acc3, 0, 0, 0);  \
} while (0)

// ---------------------------------------------------------------------------
__global__ __launch_bounds__(1024)
void fused_gc16c(const float* __restrict__ x,
                 const float* __restrict__ bq, const float* __restrict__ bk,
                 const float* __restrict__ bv, const float* __restrict__ bfb,
                 const uint4* __restrict__ wfrag,
                 float* __restrict__ out) {
  // 64KB static LDS: q/k/att [16 t][64 blk x 16B] (blk key ^(t&7)); v stream.
  // 2 WGs/CU with 32KB slack (R14's 80KBx2 = exactly 160KB did NOT fit).
  __shared__ __align__(16) unsigned short s_q  [16 * 512];
  __shared__ __align__(16) unsigned short s_k  [16 * 512];
  __shared__ __align__(16) unsigned short s_v  [16 * 512];
  __shared__ __align__(16) unsigned short s_att[16 * 512];

  const int tid  = threadIdx.x;
  const int g    = tid >> 6;      // 16 waves: wave = g (PH1/PH3) = token t (PH2)
  const int lane = tid & 63;
  const int lr   = lane & 15;
  const int lq   = lane >> 4;
  const long tok0 = (long)blockIdx.x * TT;

  // x fragments: token row lr, channel block g
  bf16x8 afr0, afr1;
  {
    const float* xr = x + (tok0 + lr) * DM + g * 64;
    afr0 = pack8(*(const float4*)(xr + 8 * lq), *(const float4*)(xr + 8 * lq + 4));
    afr1 = pack8(*(const float4*)(xr + 32 + 8 * lq), *(const float4*)(xr + 32 + 8 * lq + 4));
  }

  f32x4 acc0, acc1, acc2, acc3;   // final-linear accumulators (nf 0..3)

  PH1(0);
  __syncthreads();                // B1
  PH2();
  __syncthreads();                // B2
  // acc init with final bias; consume att(h0); build h1 q/k/v (distinct bufs)
  {
    float4 b0 = *(const float4*)&bfb[g * 64 +  0 + 4 * lq];
    float4 b1 = *(const float4*)&bfb[g * 64 + 16 + 4 * lq];
    float4 b2 = *(const float4*)&bfb[g * 64 + 32 + 4 * lq];
    float4 b3 = *(const float4*)&bfb[g * 64 + 48 + 4 * lq];
    acc0[0] = b0.x; acc0[1] = b0.y; acc0[2] = b0.z; acc0[3] = b0.w;
    acc1[0] = b1.x; acc1[1] = b1.y; acc1[2] = b1.z; acc1[3] = b1.w;
    acc2[0] = b2.x; acc2[1] = b2.y; acc2[2] = b2.z; acc2[3] = b2.w;
    acc3[0] = b3.x; acc3[1] = b3.y; acc3[2] = b3.z; acc3[3] = b3.w;
  }
  PH3(0);
  PH1(1);
  __syncthreads();                // B3  (att(h0) reads done; PH2 may rewrite)
  PH2();
  __syncthreads();                // B4
  PH3(1);

  // store out: D[o][t] -> one float4 per nf
  {
    float* orow = out + (tok0 + lr) * DM + g * 64 + 4 * lq;
    float4 o4;
    o4.x = acc0[0]; o4.y = acc0[1]; o4.z = acc0[2]; o4.w = acc0[3];
    *(float4*)(orow +  0) = o4;
    o4.x = acc1[0]; o4.y = acc1[1]; o4.z = acc1[2]; o4.w = acc1[3];
    *(float4*)(orow + 16) = o4;
    o4.x = acc2[0]; o4.y = acc2[1]; o4.z = acc2[2]; o4.w = acc2[3];
    *(float4*)(orow + 32) = o4;
    o4.x = acc3[0]; o4.y = acc3[1]; o4.z = acc3[2]; o4.w = acc3[3];
    *(float4*)(orow + 48) = o4;
  }
}

// ---------------------------------------------------------------------------
extern "C" void kernel_launch(void* const* d_in, const int* in_sizes, int n_in,
                              void* d_out, int out_size, void* d_ws, size_t ws_size,
                              hipStream_t stream) {
  const float* x   = (const float*)d_in[0];
  const float* wq  = (const float*)d_in[1];
  const float* bq_ = (const float*)d_in[2];
  const float* wk  = (const float*)d_in[3];
  const float* bk_ = (const float*)d_in[4];
  const float* wv  = (const float*)d_in[5];
  const float* bv_ = (const float*)d_in[6];
  const float* wf  = (const float*)d_in[7];
  const float* bf_ = (const float*)d_in[8];
  (void)in_sizes; (void)n_in; (void)out_size; (void)ws_size;

  uint4* wfrag = (uint4*)d_ws;   // 4*16*2*4*64 frags * 16B = 512 KiB

  build_wfrag<<<128, 256, 0, stream>>>(wq, wk, wv, wf, wfrag);
  fused_gc16c<<<NTOK / TT, 1024, 0, stream>>>(x, bq_, bk_, bv_, bf_, wfrag,
                                              (float*)d_out);
}